// Round 1
// baseline (139.989 us; speedup 1.0000x reference)
//
#include <hip/hip_runtime.h>
#include <cstdint>
#include <cstddef>

// Problem constants (from reference)
#define B_SZ   512
#define DIN    256
#define DOUT   256
#define KNOTS  64
#define NK     63          // intervals = KNOTS-1
#define HSTEP  (4.0f / 63.0f)

// ---- PCHIP slope helpers (match reference semantics exactly, f32) ----
static __device__ __forceinline__ float pchip_edge(float dA, float dB) {
    // m = (3*dA - dB)/2; zero if m*dA <= 0; clamp to 3*dA if sign flip & too big
    float m = 0.5f * (3.0f * dA - dB);
    if (m * dA <= 0.0f) {
        m = 0.0f;
    } else if (dA * dB < 0.0f && fabsf(m) > 3.0f * fabsf(dA)) {
        m = 3.0f * dA;
    }
    return m;
}

static __device__ __forceinline__ float pchip_inner(float d0, float d1) {
    if (d0 * d1 > 0.0f) {
        float denom = d0 + d1;
        if (fabsf(denom) < 1e-12f) return 0.0f;
        return 2.0f * d0 * d1 / denom;
    }
    return 0.0f;
}

// ---- Kernel 1: build cubic coefficient table ----
// ct[((i*NK + k)*DOUT + o)] = {c0,c1,c2,c3} so that
//   f(u) = c0 + u*(c1 + u*(c2 + u*c3)) == hermite interpolant on interval k.
// One block per input dim i, one thread per output dim o.
// Each thread streams its y-row y[i,o,0..63] with a 3-element window.
__global__ __launch_bounds__(256) void build_coeffs(const float* __restrict__ y,
                                                    float4* __restrict__ ct) {
    const int i = blockIdx.x;
    const int o = threadIdx.x;
    const float h = HSTEP;

    const float* r = y + ((size_t)i * DOUT + o) * KNOTS;

    float y0 = r[0], y1 = r[1], y2 = r[2];
    float d0  = (y1 - y0) / h;     // delta_k   (k starts at 0)
    float d1  = (y2 - y1) / h;     // delta_{k+1}
    float dm1 = 0.0f;              // delta_{k-1} (valid once k>=1)
    float mk  = pchip_edge(d0, d1); // m[0]

    float4* outb = ct + (size_t)i * NK * DOUT + o;

#pragma unroll 1
    for (int k = 0; k < NK; ++k) {
        float mk1;
        if (k < NK - 1) mk1 = pchip_inner(d0, d1);   // m[k+1] from delta_k, delta_{k+1}
        else            mk1 = pchip_edge(d0, dm1);   // m[63] from delta_62, delta_61

        float hm0 = h * mk, hm1 = h * mk1;
        float c2 = 3.0f * (y1 - y0) - 2.0f * hm0 - hm1;
        float c3 = 2.0f * (y0 - y1) + hm0 + hm1;
        outb[(size_t)k * DOUT] = make_float4(y0, hm0, c2, c3);

        if (k < NK - 1) {
            dm1 = d0; d0 = d1;
            y0 = y1; y1 = y2;
            if (k < NK - 2) { y2 = r[k + 3]; d1 = (y2 - y1) / h; }
            mk = mk1;
        }
    }
}

// ---- Kernel 2: forward pass ----
// One block per sample b; thread t owns output dim o=t.
// Phase 1: thread t computes (interval k, fraction u) for input dim i=t.
// Phase 2: accumulate over all 256 input dims; one coalesced float4 load each.
__global__ __launch_bounds__(256) void kan_forward(const float* __restrict__ x,
                                                   const float4* __restrict__ ct,
                                                   const float* __restrict__ bias,
                                                   float* __restrict__ out) {
    __shared__ int   soff[DIN];
    __shared__ float su[DIN];

    const int b   = blockIdx.x;
    const int tid = threadIdx.x;
    const float h = HSTEP;

    {
        float xv = x[b * DIN + tid];
        float xc = fminf(fmaxf(xv, -2.0f), 2.0f);
        float t  = (xc + 2.0f) / h;
        int k = (int)floorf(t);
        k = k < 0 ? 0 : (k > NK - 1 ? NK - 1 : k);
        soff[tid] = (tid * NK + k) * DOUT;   // float4-element offset of row
        su[tid]   = t - (float)k;
    }
    __syncthreads();

    const int o = tid;
    float acc = 0.0f;
#pragma unroll 8
    for (int i = 0; i < DIN; ++i) {
        float4 c = ct[soff[i] + o];
        float  u = su[i];
        acc += fmaf(u, fmaf(u, fmaf(u, c.w, c.z), c.y), c.x);
    }
    out[b * DOUT + o] = acc + bias[o];
}

// ---- Fallback: no-workspace path (only if ws_size is too small) ----
__global__ __launch_bounds__(256) void kan_naive(const float* __restrict__ x,
                                                 const float* __restrict__ y,
                                                 const float* __restrict__ bias,
                                                 float* __restrict__ out) {
    __shared__ int   sk[DIN];
    __shared__ float su[DIN];

    const int b   = blockIdx.x;
    const int tid = threadIdx.x;
    const float h = HSTEP;

    {
        float xv = x[b * DIN + tid];
        float xc = fminf(fmaxf(xv, -2.0f), 2.0f);
        float t  = (xc + 2.0f) / h;
        int k = (int)floorf(t);
        k = k < 0 ? 0 : (k > NK - 1 ? NK - 1 : k);
        sk[tid] = k;
        su[tid] = t - (float)k;
    }
    __syncthreads();

    const int o = tid;
    float acc = 0.0f;
    for (int i = 0; i < DIN; ++i) {
        int   k = sk[i];
        float u = su[i];
        const float* r = y + ((size_t)i * DOUT + o) * KNOTS;
        float ym1 = r[k > 0 ? k - 1 : 0];
        float y0  = r[k];
        float y1  = r[k + 1];
        float y2  = r[k < NK - 1 ? k + 2 : KNOTS - 1];
        float dm1 = (y0 - ym1) / h;
        float d0  = (y1 - y0) / h;
        float d1  = (y2 - y1) / h;
        float mk  = (k == 0)      ? pchip_edge(d0, d1)  : pchip_inner(dm1, d0);
        float mk1 = (k == NK - 1) ? pchip_edge(d0, dm1) : pchip_inner(d0, d1);
        float hm0 = h * mk, hm1 = h * mk1;
        float c2 = 3.0f * (y1 - y0) - 2.0f * hm0 - hm1;
        float c3 = 2.0f * (y0 - y1) + hm0 + hm1;
        acc += fmaf(u, fmaf(u, fmaf(u, c3, c2), hm0), y0);
    }
    out[b * DOUT + o] = acc + bias[o];
}

extern "C" void kernel_launch(void* const* d_in, const int* in_sizes, int n_in,
                              void* d_out, int out_size, void* d_ws, size_t ws_size,
                              hipStream_t stream) {
    const float* x    = (const float*)d_in[0];   // (B, DIN)
    const float* y    = (const float*)d_in[1];   // (DIN, DOUT, KNOTS)
    const float* bias = (const float*)d_in[2];   // (DOUT,)
    float* out        = (float*)d_out;           // (B, DOUT)

    const size_t need = (size_t)DIN * NK * DOUT * sizeof(float4); // ~66 MB

    if (ws_size >= need) {
        float4* ct = (float4*)d_ws;
        build_coeffs<<<dim3(DIN), dim3(256), 0, stream>>>(y, ct);
        kan_forward<<<dim3(B_SZ), dim3(256), 0, stream>>>(x, ct, bias, out);
    } else {
        kan_naive<<<dim3(B_SZ), dim3(256), 0, stream>>>(x, y, bias, out);
    }
}

// Round 2
// 101.138 us; speedup vs baseline: 1.3841x; 1.3841x over previous
//
#include <hip/hip_runtime.h>
#include <hip/hip_fp16.h>
#include <cstdint>
#include <cstddef>

// Problem constants (from reference)
#define B_SZ   512
#define DIN    256
#define DOUT   256
#define KNOTS  64
#define NK     63          // intervals = KNOTS-1
#define HSTEP  (4.0f / 63.0f)

// ---- PCHIP slope helpers (match reference semantics exactly, f32) ----
static __device__ __forceinline__ float pchip_edge(float dA, float dB) {
    // m = (3*dA - dB)/2; zero if m*dA <= 0; clamp to 3*dA if sign flip & too big
    float m = 0.5f * (3.0f * dA - dB);
    if (m * dA <= 0.0f) {
        m = 0.0f;
    } else if (dA * dB < 0.0f && fabsf(m) > 3.0f * fabsf(dA)) {
        m = 3.0f * dA;
    }
    return m;
}

static __device__ __forceinline__ float pchip_inner(float d0, float d1) {
    if (d0 * d1 > 0.0f) {
        float denom = d0 + d1;
        if (fabsf(denom) < 1e-12f) return 0.0f;
        return 2.0f * d0 * d1 / denom;
    }
    return 0.0f;
}

// ---- Kernel 1: build knot table ----
// T[(i*KNOTS + k)*DOUT + o] = __half2{ y[i,o,k], h*m[i,o,k] }
// 16.8 MB total (4 B per entry) — 4x smaller than the cubic-coeff table.
// One block per input dim i, one thread per output dim o. Each thread loads
// its y-row (64 floats, float4-vectorized), computes all 64 pchip slopes,
// writes 64 coalesced half2 stores.
__global__ __launch_bounds__(256) void build_ym(const float* __restrict__ y,
                                                __half2* __restrict__ T) {
    const int i = blockIdx.x;
    const int o = threadIdx.x;
    const float h = HSTEP;

    const float4* r4 = (const float4*)(y + ((size_t)i * DOUT + o) * KNOTS);
    float yv[KNOTS];
#pragma unroll
    for (int q = 0; q < KNOTS / 4; ++q) {
        float4 v = r4[q];
        yv[4 * q + 0] = v.x; yv[4 * q + 1] = v.y;
        yv[4 * q + 2] = v.z; yv[4 * q + 3] = v.w;
    }
    float d[NK];
#pragma unroll
    for (int k = 0; k < NK; ++k) d[k] = (yv[k + 1] - yv[k]) / h;

    __half2* outp = T + (size_t)i * KNOTS * DOUT + o;

    float m0 = pchip_edge(d[0], d[1]);
    outp[0] = __floats2half2_rn(yv[0], h * m0);
#pragma unroll
    for (int k = 1; k < NK; ++k) {
        float mk = pchip_inner(d[k - 1], d[k]);
        outp[(size_t)k * DOUT] = __floats2half2_rn(yv[k], h * mk);
    }
    float mN = pchip_edge(d[NK - 1], d[NK - 2]);
    outp[(size_t)NK * DOUT] = __floats2half2_rn(yv[KNOTS - 1], h * mN);
}

// ---- Kernel 2: forward pass ----
// One block per sample b; thread t owns output dim o=t.
// Phase 1: thread t computes (interval k, fraction u) for input dim i=t.
// Phase 2: accumulate over 256 input dims; two coalesced 4 B loads per term
// (knots k and k+1), rebuild the hermite cubic in registers.
__global__ __launch_bounds__(256) void kan_forward(const float* __restrict__ x,
                                                   const __half2* __restrict__ T,
                                                   const float* __restrict__ bias,
                                                   float* __restrict__ out) {
    __shared__ int   soff[DIN];
    __shared__ float su[DIN];

    const int b   = blockIdx.x;
    const int tid = threadIdx.x;

    {
        float xv = x[b * DIN + tid];
        float xc = fminf(fmaxf(xv, -2.0f), 2.0f);
        float t  = (xc + 2.0f) / HSTEP;
        int k = (int)floorf(t);
        k = k < 0 ? 0 : (k > NK - 1 ? NK - 1 : k);
        soff[tid] = (tid * KNOTS + k) * DOUT;   // half2-element offset of knot row
        su[tid]   = t - (float)k;
    }
    __syncthreads();

    const int o = tid;
    float acc = 0.0f;
#pragma unroll 8
    for (int i = 0; i < DIN; ++i) {
        const int off = soff[i] + o;
        float2 p0 = __half22float2(T[off]);          // {y0, h*m0}
        float2 p1 = __half22float2(T[off + DOUT]);   // {y1, h*m1}
        float u   = su[i];
        float y0 = p0.x, hm0 = p0.y;
        float y1 = p1.x, hm1 = p1.y;
        float dy = y1 - y0;
        float a2 = 3.0f * dy - 2.0f * hm0 - hm1;     // u^2 coeff
        float a3 = hm0 + hm1 - 2.0f * dy;            // u^3 coeff
        acc += fmaf(u, fmaf(u, fmaf(u, a3, a2), hm0), y0);
    }
    out[b * DOUT + o] = acc + bias[o];
}

// ---- Fallback: no-workspace path (only if ws_size is too small) ----
__global__ __launch_bounds__(256) void kan_naive(const float* __restrict__ x,
                                                 const float* __restrict__ y,
                                                 const float* __restrict__ bias,
                                                 float* __restrict__ out) {
    __shared__ int   sk[DIN];
    __shared__ float su[DIN];

    const int b   = blockIdx.x;
    const int tid = threadIdx.x;
    const float h = HSTEP;

    {
        float xv = x[b * DIN + tid];
        float xc = fminf(fmaxf(xv, -2.0f), 2.0f);
        float t  = (xc + 2.0f) / h;
        int k = (int)floorf(t);
        k = k < 0 ? 0 : (k > NK - 1 ? NK - 1 : k);
        sk[tid] = k;
        su[tid] = t - (float)k;
    }
    __syncthreads();

    const int o = tid;
    float acc = 0.0f;
    for (int i = 0; i < DIN; ++i) {
        int   k = sk[i];
        float u = su[i];
        const float* r = y + ((size_t)i * DOUT + o) * KNOTS;
        float ym1 = r[k > 0 ? k - 1 : 0];
        float y0  = r[k];
        float y1  = r[k + 1];
        float y2  = r[k < NK - 1 ? k + 2 : KNOTS - 1];
        float dm1 = (y0 - ym1) / h;
        float d0  = (y1 - y0) / h;
        float d1  = (y2 - y1) / h;
        float mk  = (k == 0)      ? pchip_edge(d0, d1)  : pchip_inner(dm1, d0);
        float mk1 = (k == NK - 1) ? pchip_edge(d0, dm1) : pchip_inner(d0, d1);
        float hm0 = h * mk, hm1 = h * mk1;
        float dy = y1 - y0;
        float c2 = 3.0f * dy - 2.0f * hm0 - hm1;
        float c3 = hm0 + hm1 - 2.0f * dy;
        acc += fmaf(u, fmaf(u, fmaf(u, c3, c2), hm0), y0);
    }
    out[b * DOUT + o] = acc + bias[o];
}

extern "C" void kernel_launch(void* const* d_in, const int* in_sizes, int n_in,
                              void* d_out, int out_size, void* d_ws, size_t ws_size,
                              hipStream_t stream) {
    const float* x    = (const float*)d_in[0];   // (B, DIN)
    const float* y    = (const float*)d_in[1];   // (DIN, DOUT, KNOTS)
    const float* bias = (const float*)d_in[2];   // (DOUT,)
    float* out        = (float*)d_out;           // (B, DOUT)

    const size_t need = (size_t)DIN * KNOTS * DOUT * sizeof(__half2); // ~16.8 MB

    if (ws_size >= need) {
        __half2* T = (__half2*)d_ws;
        build_ym<<<dim3(DIN), dim3(256), 0, stream>>>(y, T);
        kan_forward<<<dim3(B_SZ), dim3(256), 0, stream>>>(x, T, bias, out);
    } else {
        kan_naive<<<dim3(B_SZ), dim3(256), 0, stream>>>(x, y, bias, out);
    }
}